// Round 1
// baseline (3393.222 us; speedup 1.0000x reference)
//
#include <hip/hip_runtime.h>
#include <cstddef>

#define TS 2048   // sequence length S
#define TD 512    // model dim D
#define TH 8      // heads
#define TDH 64    // head dim

// ---------------------------------------------------------------------------
// GEMM: C[M,N] = A[M,K] @ W[K,N] + bias[N]
// BM=BN=64, BK=16, 256 threads, 4x4 micro-tile per thread.
// ---------------------------------------------------------------------------
__global__ __launch_bounds__(256) void gemm_bias(
    const float* __restrict__ A, const float* __restrict__ W,
    const float* __restrict__ bias, float* __restrict__ C,
    int M, int N, int Kd)
{
  __shared__ float As[16][68];   // [k][m], padded
  __shared__ float Bs[16][68];   // [k][n], padded

  const int tid = threadIdx.x;
  const int tx = tid & 15;       // N direction, 4 cols each
  const int ty = tid >> 4;       // M direction, 4 rows each
  const int rowBase = blockIdx.x * 64;
  const int colBase = blockIdx.y * 64;

  // A-tile loader mapping: 64x16 floats = 256 float4, one per thread
  const int ar = tid >> 2;             // row in tile 0..63
  const int ac = (tid & 3) << 2;       // k-col 0,4,8,12
  // B-tile loader mapping: 16x64 floats = 256 float4, one per thread
  const int brk = tid >> 4;            // k-row 0..15
  const int bc  = (tid & 15) << 2;     // n-col 0..60

  float acc[4][4] = {};

  for (int kt = 0; kt < Kd; kt += 16) {
    float4 av = *(const float4*)&A[(size_t)(rowBase + ar) * Kd + kt + ac];
    float4 bv = *(const float4*)&W[(size_t)(kt + brk) * N + colBase + bc];
    As[ac + 0][ar] = av.x;
    As[ac + 1][ar] = av.y;
    As[ac + 2][ar] = av.z;
    As[ac + 3][ar] = av.w;
    *(float4*)&Bs[brk][bc] = bv;
    __syncthreads();
#pragma unroll
    for (int k = 0; k < 16; ++k) {
      float4 a = *(const float4*)&As[k][ty << 2];
      float4 b = *(const float4*)&Bs[k][tx << 2];
      acc[0][0] += a.x * b.x; acc[0][1] += a.x * b.y; acc[0][2] += a.x * b.z; acc[0][3] += a.x * b.w;
      acc[1][0] += a.y * b.x; acc[1][1] += a.y * b.y; acc[1][2] += a.y * b.z; acc[1][3] += a.y * b.w;
      acc[2][0] += a.z * b.x; acc[2][1] += a.z * b.y; acc[2][2] += a.z * b.z; acc[2][3] += a.z * b.w;
      acc[3][0] += a.w * b.x; acc[3][1] += a.w * b.y; acc[3][2] += a.w * b.z; acc[3][3] += a.w * b.w;
    }
    __syncthreads();
  }

  float4 bb = *(const float4*)&bias[colBase + (tx << 2)];
#pragma unroll
  for (int i = 0; i < 4; ++i) {
    float4 o;
    o.x = acc[i][0] + bb.x;
    o.y = acc[i][1] + bb.y;
    o.z = acc[i][2] + bb.z;
    o.w = acc[i][3] + bb.w;
    *(float4*)&C[(size_t)(rowBase + (ty << 2) + i) * N + colBase + (tx << 2)] = o;
  }
}

// ---------------------------------------------------------------------------
// Fused attention: one block per (b, q) row, 256 threads.
// Per head: logits (q_h . K_h rows), sparsemax via Michelot (exact), sparse PV.
// avg_attention accumulated across heads in LDS, written dense once.
// ---------------------------------------------------------------------------
__global__ __launch_bounds__(256) void attn_kernel(
    const float* __restrict__ Q, const float* __restrict__ K,
    const float* __restrict__ V, float* __restrict__ heads,
    float* __restrict__ avg)
{
  __shared__ float z[TS];          // logits, then p values
  __shared__ float accum[TS];      // sum of probs over heads
  __shared__ float qv[TD];         // this row's full q vector (all heads)
  __shared__ float redS[4], redC[4], redM[4];
  __shared__ int   nz[TS];         // compacted support indices
  __shared__ int   nzcount;
  __shared__ float hpart[4][TDH];  // per-wave PV partials

  const int tid  = threadIdx.x;
  const int row  = blockIdx.x;       // b*S + q
  const int b    = row >> 11;        // / 2048
  const int lane = tid & 63;
  const int wid  = tid >> 6;

  for (int i = tid; i < TD; i += 256) qv[i] = Q[(size_t)row * TD + i];
  for (int i = tid; i < TS; i += 256) accum[i] = 0.f;

  const float* Kb = K + (size_t)b * TS * TD;
  const float* Vb = V + (size_t)b * TS * TDH;
  __syncthreads();

  for (int h = 0; h < TH; ++h) {
    // q_h into registers (LDS broadcast reads)
    float4 qreg[16];
#pragma unroll
    for (int i = 0; i < 16; ++i) qreg[i] = *(const float4*)&qv[h * TDH + (i << 2)];

    // logits: thread handles rows j = tid, tid+256, ...
    for (int jj = 0; jj < 8; ++jj) {
      const int j = (jj << 8) + tid;
      const float* kr = Kb + (size_t)j * TD + h * TDH;
      float s0 = 0.f, s1 = 0.f, s2 = 0.f, s3 = 0.f;
#pragma unroll
      for (int i = 0; i < 16; ++i) {
        float4 kv = *(const float4*)(kr + (i << 2));
        s0 += kv.x * qreg[i].x;
        s1 += kv.y * qreg[i].y;
        s2 += kv.z * qreg[i].z;
        s3 += kv.w * qreg[i].w;
      }
      z[j] = (s0 + s1) + (s2 + s3);
    }
    __syncthreads();

    // --- max reduce (seed tau = zmax - 1, a valid Michelot superset start) ---
    float lmax = -1e30f;
#pragma unroll
    for (int jj = 0; jj < 8; ++jj) lmax = fmaxf(lmax, z[(jj << 8) + tid]);
    for (int off = 32; off; off >>= 1) lmax = fmaxf(lmax, __shfl_down(lmax, off));
    if (lane == 0) redM[wid] = lmax;
    __syncthreads();
    float tau = fmaxf(fmaxf(redM[0], redM[1]), fmaxf(redM[2], redM[3])) - 1.0f;

    // --- Michelot iterations: tau -> (sum_{z>tau} z - 1)/count, to fixpoint ---
    int cnt_prev = -1;
    for (int it = 0; it < 64; ++it) {
      float ls = 0.f, lc = 0.f;
#pragma unroll
      for (int jj = 0; jj < 8; ++jj) {
        float v = z[(jj << 8) + tid];
        if (v > tau) { ls += v; lc += 1.f; }
      }
      for (int off = 32; off; off >>= 1) {
        ls += __shfl_down(ls, off);
        lc += __shfl_down(lc, off);
      }
      if (lane == 0) { redS[wid] = ls; redC[wid] = lc; }
      __syncthreads();
      const float ts = (redS[0] + redS[1]) + (redS[2] + redS[3]);
      const float tc = (redC[0] + redC[1]) + (redC[2] + redC[3]);
      tau = (ts - 1.f) / tc;
      const int cnt = (int)tc;
      __syncthreads();   // protect redS/redC before next iteration's writes
      if (cnt == cnt_prev) break;
      cnt_prev = cnt;
    }

    // --- p = relu(z - tau); compact support; accumulate avg-attention ---
    if (tid == 0) nzcount = 0;
    __syncthreads();
    for (int jj = 0; jj < 8; ++jj) {
      const int j = (jj << 8) + tid;
      const float p = z[j] - tau;
      if (p > 0.f) {
        z[j] = p;
        accum[j] += p;               // j owned by exactly one thread: no race
        nz[atomicAdd(&nzcount, 1)] = j;
      }
    }
    __syncthreads();

    // --- sparse PV: heads[row, h*64 + d] = sum_j p[j] * V[b, j, d] ---
    const int nnz = nzcount;
    float sum = 0.f;
    for (int i = wid; i < nnz; i += 4) {
      const int j = nz[i];
      sum += z[j] * Vb[(size_t)j * TDH + lane];
    }
    hpart[wid][lane] = sum;
    __syncthreads();
    if (tid < TDH) {
      heads[(size_t)row * TD + h * TDH + tid] =
          (hpart[0][tid] + hpart[1][tid]) + (hpart[2][tid] + hpart[3][tid]);
    }
    __syncthreads();   // hpart/z reuse next head
  }

  // avg_attention row (mean over 8 heads)
  const size_t base = (size_t)row * TS;
  for (int i = tid; i < TS; i += 256) avg[base + i] = accum[i] * 0.125f;
}

// ---------------------------------------------------------------------------
extern "C" void kernel_launch(void* const* d_in, const int* in_sizes, int n_in,
                              void* d_out, int out_size, void* d_ws, size_t ws_size,
                              hipStream_t stream) {
  (void)in_sizes; (void)n_in; (void)out_size; (void)ws_size;

  const float* x    = (const float*)d_in[0];
  const float* Wq   = (const float*)d_in[1];
  const float* bq   = (const float*)d_in[2];
  const float* Wk   = (const float*)d_in[3];
  const float* bk   = (const float*)d_in[4];
  const float* Wv   = (const float*)d_in[5];
  const float* bv   = (const float*)d_in[6];
  const float* Wout = (const float*)d_in[7];
  const float* bout = (const float*)d_in[8];

  float* out   = (float*)d_out;
  float* x_out = out;                       // 2*2048*512 = 2097152 floats
  float* avg   = out + 2097152;             // 2*2048*2048 floats

  float* ws = (float*)d_ws;
  float* Qb = ws;                           // 4096*512
  float* Kb = ws + 2097152;                 // 4096*512
  float* Vb = ws + 4194304;                 // 4096*64
  float* Hd = ws + 4456448;                 // 4096*512  (concat head outputs)

  const dim3 blk(256);
  const int BS = 2 * TS;                    // 4096 rows

  gemm_bias<<<dim3(BS / 64, TD / 64), blk, 0, stream>>>(x, Wq, bq, Qb, BS, TD, TD);
  gemm_bias<<<dim3(BS / 64, TD / 64), blk, 0, stream>>>(x, Wk, bk, Kb, BS, TD, TD);
  gemm_bias<<<dim3(BS / 64, TDH / 64), blk, 0, stream>>>(x, Wv, bv, Vb, BS, TDH, TD);

  attn_kernel<<<dim3(BS), blk, 0, stream>>>(Qb, Kb, Vb, Hd, avg);

  gemm_bias<<<dim3(BS / 64, TD / 64), blk, 0, stream>>>(Hd, Wout, bout, x_out, BS, TD, TD);
}

// Round 2
// 490.574 us; speedup vs baseline: 6.9168x; 6.9168x over previous
//
#include <hip/hip_runtime.h>
#include <cstddef>
#include <cstdint>

#define TS 2048   // sequence length S
#define TD 512    // model dim D
#define TH 8      // heads
#define TDH 64    // head dim
#define CAP 64    // sparse support cap per row (dense fallback beyond)

// ---------------------------------------------------------------------------
// GEMM: C[M,N] = A[M,K] @ W[K,N] + bias[N]   (projections; proven in R1)
// ---------------------------------------------------------------------------
__global__ __launch_bounds__(256) void gemm_bias(
    const float* __restrict__ A, const float* __restrict__ W,
    const float* __restrict__ bias, float* __restrict__ C,
    int M, int N, int Kd)
{
  __shared__ float As[16][68];
  __shared__ float Bs[16][68];

  const int tid = threadIdx.x;
  const int tx = tid & 15;
  const int ty = tid >> 4;
  const int rowBase = blockIdx.x * 64;
  const int colBase = blockIdx.y * 64;

  const int ar = tid >> 2;
  const int ac = (tid & 3) << 2;
  const int brk = tid >> 4;
  const int bc  = (tid & 15) << 2;

  float acc[4][4] = {};

  for (int kt = 0; kt < Kd; kt += 16) {
    float4 av = *(const float4*)&A[(size_t)(rowBase + ar) * Kd + kt + ac];
    float4 bv = *(const float4*)&W[(size_t)(kt + brk) * N + colBase + bc];
    As[ac + 0][ar] = av.x;
    As[ac + 1][ar] = av.y;
    As[ac + 2][ar] = av.z;
    As[ac + 3][ar] = av.w;
    *(float4*)&Bs[brk][bc] = bv;
    __syncthreads();
#pragma unroll
    for (int k = 0; k < 16; ++k) {
      float4 a = *(const float4*)&As[k][ty << 2];
      float4 b = *(const float4*)&Bs[k][tx << 2];
      acc[0][0] += a.x * b.x; acc[0][1] += a.x * b.y; acc[0][2] += a.x * b.z; acc[0][3] += a.x * b.w;
      acc[1][0] += a.y * b.x; acc[1][1] += a.y * b.y; acc[1][2] += a.y * b.z; acc[1][3] += a.y * b.w;
      acc[2][0] += a.z * b.x; acc[2][1] += a.z * b.y; acc[2][2] += a.z * b.z; acc[2][3] += a.z * b.w;
      acc[3][0] += a.w * b.x; acc[3][1] += a.w * b.y; acc[3][2] += a.w * b.z; acc[3][3] += a.w * b.w;
    }
    __syncthreads();
  }

  float4 bb = *(const float4*)&bias[colBase + (tx << 2)];
#pragma unroll
  for (int i = 0; i < 4; ++i) {
    float4 o;
    o.x = acc[i][0] + bb.x;
    o.y = acc[i][1] + bb.y;
    o.z = acc[i][2] + bb.z;
    o.w = acc[i][3] + bb.w;
    *(float4*)&C[(size_t)(rowBase + (ty << 2) + i) * N + colBase + (tx << 2)] = o;
  }
}

// ---------------------------------------------------------------------------
// Z = Q_h K_h^T per (b,h): NT GEMM, K-depth 64 (one LDS stage), 128x128 tile,
// 8x8 micro-tile. Unit = (pair, row-block of RB). Z written to a chunk slot.
// slot layout (floats): [Z: RB*TS][idx: RB*CAP (int)][val: RB*CAP][nnz: RB (int)]
// ---------------------------------------------------------------------------
__global__ __launch_bounds__(256) void zgemm_nt(
    const float* __restrict__ Q, const float* __restrict__ K,
    float* __restrict__ Zws, size_t slotStride, int u0, int upShift, int RB)
{
  __shared__ float As[64][129];   // [k][m], odd pad: bank = (k+m)%32
  __shared__ float Bs[64][129];   // [k][n]

  const int tid  = threadIdx.x;
  const int unit = u0 + blockIdx.z;
  const int pair = unit >> upShift;
  const int rb   = unit & ((1 << upShift) - 1);
  const int b    = pair >> 3;
  const int h    = pair & 7;

  const int qRow0 = b * TS + rb * RB + blockIdx.y * 128;  // rows in Q matrix
  const int n0    = blockIdx.x * 128;                     // cols (k-rows) in K
  float* Zp = Zws + (size_t)blockIdx.z * slotStride;      // [RB][TS]

  const float* Qbase = Q + (size_t)qRow0 * TD + h * TDH;
  const float* Kbase = K + ((size_t)(b * TS + n0)) * TD + h * TDH;

  // stage 128 rows x 64 cols of each operand, transposed into [k][m]
#pragma unroll
  for (int i = 0; i < 8; ++i) {
    const int idx = i * 256 + tid;
    const int m  = idx >> 4;
    const int k4 = (idx & 15) << 2;
    float4 a = *(const float4*)(Qbase + (size_t)m * TD + k4);
    As[k4 + 0][m] = a.x; As[k4 + 1][m] = a.y; As[k4 + 2][m] = a.z; As[k4 + 3][m] = a.w;
    float4 bb = *(const float4*)(Kbase + (size_t)m * TD + k4);
    Bs[k4 + 0][m] = bb.x; Bs[k4 + 1][m] = bb.y; Bs[k4 + 2][m] = bb.z; Bs[k4 + 3][m] = bb.w;
  }
  __syncthreads();

  const int tx8 = (tid & 15) << 3;
  const int ty8 = (tid >> 4) << 3;

  float acc[8][8] = {};
#pragma unroll 4
  for (int k = 0; k < 64; ++k) {
    float4 a0 = *(const float4*)&As[k][ty8];
    float4 a1 = *(const float4*)&As[k][ty8 + 4];
    float4 b0 = *(const float4*)&Bs[k][tx8];
    float4 b1 = *(const float4*)&Bs[k][tx8 + 4];
    float av[8] = {a0.x, a0.y, a0.z, a0.w, a1.x, a1.y, a1.z, a1.w};
    float bv[8] = {b0.x, b0.y, b0.z, b0.w, b1.x, b1.y, b1.z, b1.w};
#pragma unroll
    for (int ii = 0; ii < 8; ++ii)
#pragma unroll
      for (int jj = 0; jj < 8; ++jj)
        acc[ii][jj] += av[ii] * bv[jj];
  }

  const int zRowBase = blockIdx.y * 128 + ((tid >> 4) << 3);  // slot-relative
#pragma unroll
  for (int ii = 0; ii < 8; ++ii) {
    float* dst = Zp + (size_t)(zRowBase + ii) * TS + n0 + tx8;
    float4 o0 = {acc[ii][0], acc[ii][1], acc[ii][2], acc[ii][3]};
    float4 o1 = {acc[ii][4], acc[ii][5], acc[ii][6], acc[ii][7]};
    *(float4*)dst = o0;
    *(float4*)(dst + 4) = o1;
  }
}

// ---------------------------------------------------------------------------
// Sparsemax per row (Michelot fixpoint, proven R1) + avg scatter + compaction.
// ---------------------------------------------------------------------------
__global__ __launch_bounds__(256) void sparsemax_rows(
    float* __restrict__ Zws, size_t slotStride, int u0, int upShift, int RB,
    float* __restrict__ avg)
{
  __shared__ float zs[TS];
  __shared__ float redS[4], redC[4], redM[4];
  __shared__ int   nzcount;

  const int tid  = threadIdx.x;
  const int lane = tid & 63;
  const int wid  = tid >> 6;
  const int unit = u0 + blockIdx.y;
  const int pair = unit >> upShift;
  const int rb   = unit & ((1 << upShift) - 1);
  const int b    = pair >> 3;
  const int q    = rb * RB + blockIdx.x;   // row within this pair's S

  float* slot = Zws + (size_t)blockIdx.y * slotStride;
  float* Zrow = slot + (size_t)blockIdx.x * TS;
  int*   idxA = (int*)(slot + (size_t)RB * TS) + (size_t)blockIdx.x * CAP;
  float* valA = slot + (size_t)RB * TS + (size_t)RB * CAP + (size_t)blockIdx.x * CAP;
  int*   nnzA = (int*)(slot + (size_t)RB * TS + 2ull * RB * CAP);

#pragma unroll
  for (int i = 0; i < 2; ++i) {
    const int j4 = (i * 256 + tid) << 2;
    *(float4*)&zs[j4] = *(const float4*)&Zrow[j4];
  }
  __syncthreads();

  // seed tau = zmax - 1
  float lmax = -1e30f;
#pragma unroll
  for (int jj = 0; jj < 8; ++jj) lmax = fmaxf(lmax, zs[(jj << 8) + tid]);
  for (int off = 32; off; off >>= 1) lmax = fmaxf(lmax, __shfl_down(lmax, off));
  if (lane == 0) redM[wid] = lmax;
  __syncthreads();
  float tau = fmaxf(fmaxf(redM[0], redM[1]), fmaxf(redM[2], redM[3])) - 1.0f;

  // Michelot: tau -> (sum_{z>tau} z - 1)/count to fixpoint
  int cnt_prev = -1;
  for (int it = 0; it < 64; ++it) {
    float ls = 0.f, lc = 0.f;
#pragma unroll
    for (int jj = 0; jj < 8; ++jj) {
      float v = zs[(jj << 8) + tid];
      if (v > tau) { ls += v; lc += 1.f; }
    }
    for (int off = 32; off; off >>= 1) {
      ls += __shfl_down(ls, off);
      lc += __shfl_down(lc, off);
    }
    if (lane == 0) { redS[wid] = ls; redC[wid] = lc; }
    __syncthreads();
    const float ts = (redS[0] + redS[1]) + (redS[2] + redS[3]);
    const float tc = (redC[0] + redC[1]) + (redC[2] + redC[3]);
    tau = (ts - 1.f) / tc;
    const int cnt = (int)tc;
    __syncthreads();
    if (cnt == cnt_prev) break;
    cnt_prev = cnt;
  }

  if (tid == 0) nzcount = 0;
  __syncthreads();

  float* avgRow = avg + ((size_t)(b * TS + q)) * TS;
#pragma unroll
  for (int jj = 0; jj < 8; ++jj) {
    const int j = (jj << 8) + tid;
    const float p = zs[j] - tau;
    if (p > 0.f) {
      const int pos = atomicAdd(&nzcount, 1);
      if (pos < CAP) { idxA[pos] = j; valA[pos] = p; }
      atomicAdd(&avgRow[j], p * 0.125f);
    }
  }
  __syncthreads();

  const int cnt = nzcount;
  if (cnt > CAP) {
    // dense fallback: write p row back in place for pv dense path
#pragma unroll
    for (int jj = 0; jj < 8; ++jj) {
      const int j = (jj << 8) + tid;
      const float p = zs[j] - tau;
      Zrow[j] = p > 0.f ? p : 0.f;
    }
  }
  if (tid == 0) nnzA[blockIdx.x] = (cnt <= CAP) ? cnt : -1;
}

// ---------------------------------------------------------------------------
// PV: one wave per (row, head); lane = head-dim. Sparse gather of V rows.
// ---------------------------------------------------------------------------
__global__ __launch_bounds__(256) void pv_sparse(
    const float* __restrict__ Zws, size_t slotStride, int u0, int upShift, int RB,
    const float* __restrict__ V, float* __restrict__ heads)
{
  const int tid  = threadIdx.x;
  const int wid  = tid >> 6;
  const int lane = tid & 63;
  const int unit = u0 + blockIdx.y;
  const int pair = unit >> upShift;
  const int rb   = unit & ((1 << upShift) - 1);
  const int b    = pair >> 3;
  const int h    = pair & 7;
  const int qLocal = blockIdx.x * 4 + wid;

  const float* slot = Zws + (size_t)blockIdx.y * slotStride;
  const int nnz = ((const int*)(slot + (size_t)RB * TS + 2ull * RB * CAP))[qLocal];
  const float* Vb = V + (size_t)b * TS * TDH;

  float acc = 0.f;
  if (nnz >= 0) {
    const int*   idxA = (const int*)(slot + (size_t)RB * TS) + (size_t)qLocal * CAP;
    const float* valA = slot + (size_t)RB * TS + (size_t)RB * CAP + (size_t)qLocal * CAP;
    for (int i = 0; i < nnz; ++i)
      acc += valA[i] * Vb[(size_t)idxA[i] * TDH + lane];
  } else {
    const float* Zrow = slot + (size_t)qLocal * TS;
    for (int j = 0; j < TS; ++j) {
      const float p = Zrow[j];
      if (p > 0.f) acc += p * Vb[(size_t)j * TDH + lane];
    }
  }

  const int q = rb * RB + qLocal;
  heads[((size_t)(b * TS + q)) * TD + h * TDH + lane] = acc;
}

// ---------------------------------------------------------------------------
extern "C" void kernel_launch(void* const* d_in, const int* in_sizes, int n_in,
                              void* d_out, int out_size, void* d_ws, size_t ws_size,
                              hipStream_t stream) {
  (void)in_sizes; (void)n_in; (void)out_size;

  const float* x    = (const float*)d_in[0];
  const float* Wq   = (const float*)d_in[1];
  const float* bq   = (const float*)d_in[2];
  const float* Wk   = (const float*)d_in[3];
  const float* bk   = (const float*)d_in[4];
  const float* Wv   = (const float*)d_in[5];
  const float* bv   = (const float*)d_in[6];
  const float* Wout = (const float*)d_in[7];
  const float* bout = (const float*)d_in[8];

  float* out   = (float*)d_out;
  float* x_out = out;                       // [2,2048,512]
  float* avg   = out + 2097152;             // [2,2048,2048]

  float* ws = (float*)d_ws;
  float* Qb = ws;                           // 4096*512
  float* Kb = ws + 2097152;                 // 4096*512
  float* Vb = ws + 4194304;                 // 4096*64
  float* Hd = ws + 4456448;                 // 4096*512
  float* Zws = ws + 6553600;                // chunk slots

  const dim3 blk(256);
  const int BS = 2 * TS;                    // 4096 rows

  // choose chunking: RB rows per unit, NS slots resident at once
  const size_t wsFloats = ws_size / 4;
  const size_t fixed = 6553600;
  const size_t avail = wsFloats > fixed ? wsFloats - fixed : 0;

  int RB, upShift, unitsTotal, NS;
  const size_t stride2048 = (size_t)2048 * TS + 2048ull * CAP * 2 + 2048;  // 17.8 MB
  const size_t stride128  = (size_t)128 * TS + 128ull * CAP * 2 + 128;     // 1.1 MB
  size_t slotStride;
  if (avail >= stride2048) {
    RB = 2048; upShift = 0; unitsTotal = 16;
    NS = (int)(avail / stride2048); if (NS > 16) NS = 16;
    slotStride = stride2048;
  } else {
    RB = 128; upShift = 4; unitsTotal = 256;
    NS = (int)(avail / stride128); if (NS < 1) NS = 1; if (NS > 256) NS = 256;
    slotStride = stride128;
  }

  // projections
  gemm_bias<<<dim3(BS / 64, TD / 64), blk, 0, stream>>>(x, Wq, bq, Qb, BS, TD, TD);
  gemm_bias<<<dim3(BS / 64, TD / 64), blk, 0, stream>>>(x, Wk, bk, Kb, BS, TD, TD);
  gemm_bias<<<dim3(BS / 64, TDH / 64), blk, 0, stream>>>(x, Wv, bv, Vb, BS, TDH, TD);

  // avg accumulated sparsely via atomics -> zero it first
  hipMemsetAsync(avg, 0, (size_t)2 * TS * TS * sizeof(float), stream);

  for (int u0 = 0; u0 < unitsTotal; u0 += NS) {
    const int nu = (unitsTotal - u0 < NS) ? (unitsTotal - u0) : NS;
    zgemm_nt<<<dim3(16, RB / 128, nu), blk, 0, stream>>>(Qb, Kb, Zws, slotStride, u0, upShift, RB);
    sparsemax_rows<<<dim3(RB, nu), blk, 0, stream>>>(Zws, slotStride, u0, upShift, RB, avg);
    pv_sparse<<<dim3(RB / 4, nu), blk, 0, stream>>>(Zws, slotStride, u0, upShift, RB, Vb, Hd);
  }

  // output projection
  gemm_bias<<<dim3(BS / 64, TD / 64), blk, 0, stream>>>(Hd, Wout, bout, x_out, BS, TD, TD);
}

// Round 3
// 424.433 us; speedup vs baseline: 7.9947x; 1.1558x over previous
//
#include <hip/hip_runtime.h>
#include <cstddef>
#include <cstdint>

#define TS 2048   // sequence length S
#define TD 512    // model dim D
#define TH 8      // heads
#define TDH 64    // head dim
#define CAP 256   // sparse support entries per row per batch

typedef float f32x4 __attribute__((ext_vector_type(4)));
typedef short short8v __attribute__((ext_vector_type(8)));

struct us4 { unsigned short a, b, c, d; };

__device__ __forceinline__ unsigned short f2bf(float f) {
  unsigned u = __builtin_bit_cast(unsigned, f);
  u += 0x7fff + ((u >> 16) & 1);          // RNE
  return (unsigned short)(u >> 16);
}

// ---------------------------------------------------------------------------
// GEMM: C[M,N] = A[M,K] @ W[K,N] + bias[N].
// mode 0: f32 row-major to C. mode 1: bf16 head-major [b,h,s,dh] to outBf.
// ---------------------------------------------------------------------------
__global__ __launch_bounds__(256) void gemm_bias(
    const float* __restrict__ A, const float* __restrict__ W,
    const float* __restrict__ bias, float* __restrict__ C,
    short* __restrict__ outBf, int mode,
    int M, int N, int Kd)
{
  __shared__ float As[16][68];
  __shared__ float Bs[16][68];

  const int tid = threadIdx.x;
  const int tx = tid & 15;
  const int ty = tid >> 4;
  const int rowBase = blockIdx.x * 64;
  const int colBase = blockIdx.y * 64;

  const int ar = tid >> 2;
  const int ac = (tid & 3) << 2;
  const int brk = tid >> 4;
  const int bc  = (tid & 15) << 2;

  float acc[4][4] = {};

  for (int kt = 0; kt < Kd; kt += 16) {
    float4 av = *(const float4*)&A[(size_t)(rowBase + ar) * Kd + kt + ac];
    float4 bv = *(const float4*)&W[(size_t)(kt + brk) * N + colBase + bc];
    As[ac + 0][ar] = av.x;
    As[ac + 1][ar] = av.y;
    As[ac + 2][ar] = av.z;
    As[ac + 3][ar] = av.w;
    *(float4*)&Bs[brk][bc] = bv;
    __syncthreads();
#pragma unroll
    for (int k = 0; k < 16; ++k) {
      float4 a = *(const float4*)&As[k][ty << 2];
      float4 b = *(const float4*)&Bs[k][tx << 2];
      acc[0][0] += a.x * b.x; acc[0][1] += a.x * b.y; acc[0][2] += a.x * b.z; acc[0][3] += a.x * b.w;
      acc[1][0] += a.y * b.x; acc[1][1] += a.y * b.y; acc[1][2] += a.y * b.z; acc[1][3] += a.y * b.w;
      acc[2][0] += a.z * b.x; acc[2][1] += a.z * b.y; acc[2][2] += a.z * b.z; acc[2][3] += a.z * b.w;
      acc[3][0] += a.w * b.x; acc[3][1] += a.w * b.y; acc[3][2] += a.w * b.z; acc[3][3] += a.w * b.w;
    }
    __syncthreads();
  }

  float4 bb = *(const float4*)&bias[colBase + (tx << 2)];
  if (mode == 0) {
#pragma unroll
    for (int i = 0; i < 4; ++i) {
      float4 o;
      o.x = acc[i][0] + bb.x;
      o.y = acc[i][1] + bb.y;
      o.z = acc[i][2] + bb.z;
      o.w = acc[i][3] + bb.w;
      *(float4*)&C[(size_t)(rowBase + (ty << 2) + i) * N + colBase + (tx << 2)] = o;
    }
  } else {
    // bf16 head-major: row = b*2048+s, col = h*64+dh
#pragma unroll
    for (int i = 0; i < 4; ++i) {
      const int row = rowBase + (ty << 2) + i;
      const int col = colBase + (tx << 2);
      const int bI = row >> 11, s = row & 2047;
      const int hI = col >> 6, dh = col & 63;
      us4 o;
      o.a = f2bf(acc[i][0] + bb.x);
      o.b = f2bf(acc[i][1] + bb.y);
      o.c = f2bf(acc[i][2] + bb.z);
      o.d = f2bf(acc[i][3] + bb.w);
      *(us4*)(outBf + (((size_t)(bI * TH + hI) * TS + s) * TDH + dh)) = o;
    }
  }
}

// ---------------------------------------------------------------------------
// Fused attention: block = (pair, 16 q-rows), 256 threads = 4 waves.
// QK^T via bf16 MFMA (Z in registers) -> Michelot sparsemax (exact fixpoint)
// -> avg atomic scatter -> sparse PV.
// MFMA C/D layout: col = lane&15, row = (lane>>4)*4 + reg.
// ---------------------------------------------------------------------------
__global__ __launch_bounds__(256) void fused_attn(
    const short* __restrict__ Qh, const short* __restrict__ Kh,
    const float* __restrict__ V, float* __restrict__ heads,
    float* __restrict__ avg)
{
  __shared__ float redS[4][16], redC[4][16];
  __shared__ int   cntS[16];
  __shared__ int   s_flag;
  __shared__ int   idxS[16][CAP];
  __shared__ float valS[16][CAP];

  const int tid  = threadIdx.x;
  const int w    = tid >> 6;
  const int lane = tid & 63;
  const int g    = lane >> 4;      // 16-lane group 0..3
  const int lc16 = lane & 15;
  const int pair = blockIdx.y;
  const int b    = pair >> 3;
  const int h    = pair & 7;
  const int q0   = blockIdx.x * 16;
  const int wcol0 = w * 512;

  // A fragments: lane holds Q[q0 + (lane&15)][g*8 .. g*8+7] (+32 for k-half 1)
  const short* Qbase = Qh + ((size_t)pair * TS + q0) * TDH;
  short8v aq0 = *(const short8v*)(Qbase + lc16 * TDH + g * 8);
  short8v aq1 = *(const short8v*)(Qbase + lc16 * TDH + 32 + g * 8);

  const short* Kb = Kh + (size_t)pair * TS * TDH;

  f32x4 acc[32];
#pragma unroll
  for (int t = 0; t < 32; ++t) acc[t] = (f32x4){0.f, 0.f, 0.f, 0.f};

  // ---- QK^T: 32 col-tiles of 16, K-depth 64 = 2 MFMAs each ----
#pragma unroll
  for (int t = 0; t < 32; ++t) {
    const short* kp = Kb + (size_t)(wcol0 + t * 16 + lc16) * TDH + g * 8;
    short8v b0 = *(const short8v*)(kp);
    short8v b1 = *(const short8v*)(kp + 32);
    acc[t] = __builtin_amdgcn_mfma_f32_16x16x32_bf16(aq0, b0, acc[t], 0, 0, 0);
    acc[t] = __builtin_amdgcn_mfma_f32_16x16x32_bf16(aq1, b1, acc[t], 0, 0, 0);
  }

  // ---- row max (seed tau = zmax - 1) ----
  float pmax[4];
#pragma unroll
  for (int i = 0; i < 4; ++i) pmax[i] = -1e30f;
#pragma unroll
  for (int t = 0; t < 32; ++t)
#pragma unroll
    for (int i = 0; i < 4; ++i) pmax[i] = fmaxf(pmax[i], acc[t][i]);
#pragma unroll
  for (int m = 1; m < 16; m <<= 1)
#pragma unroll
    for (int i = 0; i < 4; ++i) pmax[i] = fmaxf(pmax[i], __shfl_xor(pmax[i], m));
  if (lc16 == 0)
#pragma unroll
    for (int i = 0; i < 4; ++i) redS[w][g * 4 + i] = pmax[i];
  __syncthreads();

  float tau[4];
  int prev[4] = {-1, -1, -1, -1};
#pragma unroll
  for (int i = 0; i < 4; ++i) {
    const int r = g * 4 + i;
    tau[i] = fmaxf(fmaxf(redS[0][r], redS[1][r]), fmaxf(redS[2][r], redS[3][r])) - 1.0f;
  }

  // ---- Michelot fixpoint: tau <- (sum_{z>tau} z - 1)/count ----
  for (int iter = 0; iter < 64; ++iter) {
    float ls[4] = {0, 0, 0, 0}, lcnt[4] = {0, 0, 0, 0};
#pragma unroll
    for (int t = 0; t < 32; ++t)
#pragma unroll
      for (int i = 0; i < 4; ++i) {
        const float v = acc[t][i];
        if (v > tau[i]) { ls[i] += v; lcnt[i] += 1.f; }
      }
#pragma unroll
    for (int m = 1; m < 16; m <<= 1)
#pragma unroll
      for (int i = 0; i < 4; ++i) {
        ls[i]   += __shfl_xor(ls[i], m);
        lcnt[i] += __shfl_xor(lcnt[i], m);
      }
    __syncthreads();                       // protect previous reads of redS/redC
    if (lc16 == 0)
#pragma unroll
      for (int i = 0; i < 4; ++i) {
        redS[w][g * 4 + i] = ls[i];
        redC[w][g * 4 + i] = lcnt[i];
      }
    if (tid == 0) s_flag = 0;
    __syncthreads();
    bool changed = false;
#pragma unroll
    for (int i = 0; i < 4; ++i) {
      const int r = g * 4 + i;
      const float ts = redS[0][r] + redS[1][r] + redS[2][r] + redS[3][r];
      const float tc = redC[0][r] + redC[1][r] + redC[2][r] + redC[3][r];
      tau[i] = (ts - 1.f) / tc;
      const int c = (int)tc;
      if (c != prev[i]) changed = true;
      prev[i] = c;
    }
    if (changed && lc16 == 0) atomicOr(&s_flag, 1);
    __syncthreads();
    if (!s_flag) break;
  }

  // ---- emission: p = relu(z - tau); avg scatter; compact to LDS ----
  if (tid < 16) cntS[tid] = 0;
  if (tid == 0) s_flag = 0;                // reuse as overflow flag
  __syncthreads();

  const int rowg = g * 4;
  float* avgBase = avg + ((size_t)b * TS + q0) * TS;
  unsigned em[4] = {0, 0, 0, 0};

#pragma unroll
  for (int t = 0; t < 32; ++t)
#pragma unroll
    for (int i = 0; i < 4; ++i) {
      const float p = acc[t][i] - tau[i];
      if (p > 0.f) {
        const int row = rowg + i;
        const int col = wcol0 + t * 16 + lc16;
        atomicAdd(avgBase + (size_t)row * TS + col, p * 0.125f);
        const int pos = atomicAdd(&cntS[row], 1);
        if (pos < CAP) { idxS[row][pos] = col; valS[row][pos] = p; }
        else em[i] |= (1u << t);
      }
    }

  // ---- sparse PV (batched for CAP overflow safety) ----
  float apv[4] = {0, 0, 0, 0};
  const float* Vb = V + (size_t)b * TS * TDH;

  for (;;) {
    __syncthreads();                       // entries + counts visible
#pragma unroll
    for (int rr = 0; rr < 4; ++rr) {
      const int r = w * 4 + rr;
      const int n = min(cntS[r], CAP);
      for (int e = 0; e < n; ++e)
        apv[rr] += valS[r][e] * Vb[(size_t)idxS[r][e] * TDH + lane];
    }
    if (tid < 16 && cntS[tid] > CAP) atomicOr(&s_flag, 1);
    __syncthreads();                       // PV reads done; s_flag visible
    if (!s_flag) break;
    if (tid < 16) cntS[tid] = 0;
    if (tid == 0) s_flag = 0;
    __syncthreads();
    // re-emit leftovers
#pragma unroll
    for (int t = 0; t < 32; ++t)
#pragma unroll
      for (int i = 0; i < 4; ++i)
        if (em[i] & (1u << t)) {
          const float p = acc[t][i] - tau[i];
          const int row = rowg + i;
          const int col = wcol0 + t * 16 + lc16;
          const int pos = atomicAdd(&cntS[row], 1);
          if (pos < CAP) {
            idxS[row][pos] = col; valS[row][pos] = p;
            em[i] &= ~(1u << t);
          }
        }
  }

  // ---- write heads ----
#pragma unroll
  for (int rr = 0; rr < 4; ++rr) {
    const int r = w * 4 + rr;
    heads[((size_t)b * TS + q0 + r) * TD + h * TDH + lane] = apv[rr];
  }
}

// ---------------------------------------------------------------------------
extern "C" void kernel_launch(void* const* d_in, const int* in_sizes, int n_in,
                              void* d_out, int out_size, void* d_ws, size_t ws_size,
                              hipStream_t stream) {
  (void)in_sizes; (void)n_in; (void)out_size; (void)ws_size;

  const float* x    = (const float*)d_in[0];
  const float* Wq   = (const float*)d_in[1];
  const float* bq   = (const float*)d_in[2];
  const float* Wk   = (const float*)d_in[3];
  const float* bk   = (const float*)d_in[4];
  const float* Wv   = (const float*)d_in[5];
  const float* bv   = (const float*)d_in[6];
  const float* Wout = (const float*)d_in[7];
  const float* bout = (const float*)d_in[8];

  float* out   = (float*)d_out;
  float* x_out = out;                       // [2,2048,512]
  float* avg   = out + 2097152;             // [2,2048,2048]

  float* ws = (float*)d_ws;
  float* Vb = ws;                           // f32 [2][2048][64]           (262144)
  float* Hd = ws + 262144;                  // f32 [4096][512]             (2097152)
  short* Qh = (short*)(ws + 2359296);       // bf16 [16][2048][64]         (1048576 fl)
  short* Kh = (short*)(ws + 3407872);       // bf16 [16][2048][64]         (1048576 fl)

  const dim3 blk(256);
  const int BS = 2 * TS;                    // 4096 rows

  // projections: Q,K -> bf16 head-major; V -> f32
  gemm_bias<<<dim3(BS / 64, TD / 64), blk, 0, stream>>>(x, Wq, bq, nullptr, Qh, 1, BS, TD, TD);
  gemm_bias<<<dim3(BS / 64, TD / 64), blk, 0, stream>>>(x, Wk, bk, nullptr, Kh, 1, BS, TD, TD);
  gemm_bias<<<dim3(BS / 64, TDH / 64), blk, 0, stream>>>(x, Wv, bv, Vb, nullptr, 0, BS, TDH, TD);

  // avg accumulated sparsely via atomics -> zero it first
  hipMemsetAsync(avg, 0, (size_t)2 * TS * TS * sizeof(float), stream);

  fused_attn<<<dim3(TS / 16, 16), blk, 0, stream>>>(Qh, Kh, Vb, Hd, avg);

  // output projection
  gemm_bias<<<dim3(BS / 64, TD / 64), blk, 0, stream>>>(Hd, Wout, bout, x_out, nullptr, 0, BS, TD, TD);
}